// Round 1
// baseline (436.678 us; speedup 1.0000x reference)
//
#include <hip/hip_runtime.h>

#define BZv 4
#define QL 512
#define CL 1536
#define KVL 2048
#define EMB 1024
#define NH 16
#define HD 64

typedef __attribute__((ext_vector_type(8))) short short8;
typedef __attribute__((ext_vector_type(4))) float floatx4;

__device__ __forceinline__ unsigned short f2b(float f) {
  union { float f; unsigned int u; } v; v.f = f;
  return (unsigned short)((v.u + 0x7FFFu + ((v.u >> 16) & 1u)) >> 16);
}

// ---------------- prep: fp32->bf16 conversions + cache copies ----------------
__global__ __launch_bounds__(256) void prep_kernel(
    const float* __restrict__ hid, const float* __restrict__ Wq, const float* __restrict__ Wk,
    const float* __restrict__ Wv, const float* __restrict__ Wo,
    const float* __restrict__ kc, const float* __restrict__ vc,
    unsigned short* __restrict__ Xb, unsigned short* __restrict__ Wqb, unsigned short* __restrict__ Wkb,
    unsigned short* __restrict__ Wvb, unsigned short* __restrict__ Wob,
    unsigned short* __restrict__ Kb, unsigned short* __restrict__ Vb,
    float* __restrict__ kf, float* __restrict__ vf)
{
  const long HID4 = (long)BZv * QL * EMB / 4;   // 524288
  const long W4   = (long)EMB * EMB / 4;        // 262144
  const long C4   = (long)BZv * CL * EMB / 4;   // 1572864
  const long t0 = HID4, t1 = t0 + W4, t2 = t1 + W4, t3 = t2 + W4, t4 = t3 + W4;
  const long t5 = t4 + C4, total = t5 + C4;
  for (long i = (long)blockIdx.x * blockDim.x + threadIdx.x; i < total;
       i += (long)gridDim.x * blockDim.x) {
    if (i < t4) {
      const float* src; unsigned short* dst; long j;
      if (i < t0)      { src = hid; dst = Xb;  j = i; }
      else if (i < t1) { src = Wq;  dst = Wqb; j = i - t0; }
      else if (i < t2) { src = Wk;  dst = Wkb; j = i - t1; }
      else if (i < t3) { src = Wv;  dst = Wvb; j = i - t2; }
      else             { src = Wo;  dst = Wob; j = i - t3; }
      float4 v = ((const float4*)src)[j];
      ushort4 o; o.x = f2b(v.x); o.y = f2b(v.y); o.z = f2b(v.z); o.w = f2b(v.w);
      ((ushort4*)dst)[j] = o;
    } else {
      bool isV = (i >= t5);
      long j = i - (isV ? t5 : t4);
      const float* src = isV ? vc : kc;
      float4 v = ((const float4*)src)[j];
      long e4 = j * 4;
      int b = (int)(e4 / ((long)CL * EMB));
      long rem = e4 - (long)b * CL * EMB;
      long doff = (long)b * KVL * EMB + rem;   // rows 0..1535 of each batch's kv block
      float* of = isV ? vf : kf;
      unsigned short* ob = isV ? Vb : Kb;
      *((float4*)(of + doff)) = v;
      ushort4 o; o.x = f2b(v.x); o.y = f2b(v.y); o.z = f2b(v.z); o.w = f2b(v.w);
      *((ushort4*)(ob + doff)) = o;
    }
  }
}

// ---------------- bf16 MFMA GEMM: C = A @ W^T + bias ----------------
// A: [2048][1024] bf16.  W: [1024][1024] bf16 (row n holds K contiguous -> B^T input).
// Each wave: 16 rows x 64 cols.  Block 256 thr = 4 waves (64x64 tile). grid (16, 32).
// remap=1: output row m -> b*2048 + 1536 + (m&511)  (KV-cache concat position)
__global__ __launch_bounds__(256) void proj_gemm(
    const unsigned short* __restrict__ A, const unsigned short* __restrict__ W,
    const float* __restrict__ bias, unsigned short* __restrict__ outb,
    float* __restrict__ outf, int remap)
{
  int lane = threadIdx.x & 63, wave = threadIdx.x >> 6;
  int quad = lane >> 4, l = lane & 15;
  int mbase = blockIdx.y * 64 + wave * 16;
  int nbase = blockIdx.x * 64;
  const unsigned short* ap = A + (size_t)(mbase + l) * EMB + quad * 8;
  const unsigned short* wp = W + (size_t)(nbase + l) * EMB + quad * 8;
  floatx4 acc0 = {0.f,0.f,0.f,0.f}, acc1 = {0.f,0.f,0.f,0.f};
  floatx4 acc2 = {0.f,0.f,0.f,0.f}, acc3 = {0.f,0.f,0.f,0.f};
#pragma unroll 4
  for (int k0 = 0; k0 < EMB; k0 += 32) {
    short8 a  = *(const short8*)(ap + k0);
    short8 b0 = *(const short8*)(wp + k0);
    short8 b1 = *(const short8*)(wp + 16 * EMB + k0);
    short8 b2 = *(const short8*)(wp + 32 * EMB + k0);
    short8 b3 = *(const short8*)(wp + 48 * EMB + k0);
    acc0 = __builtin_amdgcn_mfma_f32_16x16x32_bf16(a, b0, acc0, 0, 0, 0);
    acc1 = __builtin_amdgcn_mfma_f32_16x16x32_bf16(a, b1, acc1, 0, 0, 0);
    acc2 = __builtin_amdgcn_mfma_f32_16x16x32_bf16(a, b2, acc2, 0, 0, 0);
    acc3 = __builtin_amdgcn_mfma_f32_16x16x32_bf16(a, b3, acc3, 0, 0, 0);
  }
  float bn0 = bias[nbase + l], bn1 = bias[nbase + 16 + l];
  float bn2 = bias[nbase + 32 + l], bn3 = bias[nbase + 48 + l];
#pragma unroll
  for (int r = 0; r < 4; r++) {
    int row = mbase + quad * 4 + r;
    size_t orow = remap ? ((size_t)(row >> 9) * KVL + CL + (row & 511)) : (size_t)row;
    float v0 = acc0[r] + bn0, v1 = acc1[r] + bn1, v2 = acc2[r] + bn2, v3 = acc3[r] + bn3;
    size_t base = orow * EMB + nbase + l;
    if (outf) { outf[base] = v0; outf[base+16] = v1; outf[base+32] = v2; outf[base+48] = v3; }
    if (outb) { outb[base] = f2b(v0); outb[base+16] = f2b(v1);
                outb[base+32] = f2b(v2); outb[base+48] = f2b(v3); }
  }
}

// ---------------- flash attention ----------------
// grid (QL/64, NH, BZ), block 256 = 4 waves. wave handles 16 q rows; kv tiles of 32.
__global__ __launch_bounds__(256) void attn_kernel(
    const unsigned short* __restrict__ Qb, const unsigned short* __restrict__ Kb,
    const unsigned short* __restrict__ Vb, const float* __restrict__ mask,
    unsigned short* __restrict__ Cb)
{
  __shared__ unsigned short Pl[4][16 * 40];  // per-wave P tile, row stride 40 (16B-aligned reads)
  __shared__ unsigned short Vl[32 * 66];     // V tile [kv][d], stride 66 -> 2-way-free banks
  int b = blockIdx.z, h = blockIdx.y, qt = blockIdx.x;
  int lane = threadIdx.x & 63, wave = threadIdx.x >> 6;
  int quad = lane >> 4, l = lane & 15;
  int qbase = qt * 64 + wave * 16;          // 0..511
  const unsigned short* qp = Qb + (size_t)(b * QL + qbase + l) * EMB + h * HD + quad * 8;
  short8 a0 = *(const short8*)qp;
  short8 a1 = *(const short8*)(qp + 32);
  floatx4 o0 = {0.f,0.f,0.f,0.f}, o1 = {0.f,0.f,0.f,0.f};
  floatx4 o2 = {0.f,0.f,0.f,0.f}, o3 = {0.f,0.f,0.f,0.f};
  float mr[4], lr[4];
#pragma unroll
  for (int r = 0; r < 4; r++) { mr[r] = -INFINITY; lr[r] = 0.f; }
  const int kv_end = CL + qt * 64 + 64;      // uniform across the block's 4 waves (<= 2048)
  int vrow = threadIdx.x >> 3, vchunk = threadIdx.x & 7;
  const unsigned short* vsrc = Vb + (size_t)(b * KVL + vrow) * EMB + h * HD + vchunk * 8;

  for (int kv0 = 0; kv0 < kv_end; kv0 += 32) {
    // cooperative V stage: 32 rows x 64 dims bf16
    {
      uint4 vv = *(const uint4*)(vsrc + (size_t)kv0 * EMB);
      unsigned int* d = (unsigned int*)&Vl[vrow * 66 + vchunk * 8];
      d[0] = vv.x; d[1] = vv.y; d[2] = vv.z; d[3] = vv.w;
    }
    // S = Q K^T for 32 kv cols (two 16-col C-tiles), K loaded direct (L1/L2 hit)
    const unsigned short* kp = Kb + (size_t)(b * KVL + kv0 + l) * EMB + h * HD + quad * 8;
    short8 k0lo = *(const short8*)kp;
    short8 k0hi = *(const short8*)(kp + 32);
    short8 k1lo = *(const short8*)(kp + 16 * EMB);
    short8 k1hi = *(const short8*)(kp + 16 * EMB + 32);
    floatx4 s0 = {0.f,0.f,0.f,0.f}, s1 = {0.f,0.f,0.f,0.f};
    s0 = __builtin_amdgcn_mfma_f32_16x16x32_bf16(a0, k0lo, s0, 0, 0, 0);
    s0 = __builtin_amdgcn_mfma_f32_16x16x32_bf16(a1, k0hi, s0, 0, 0, 0);
    s1 = __builtin_amdgcn_mfma_f32_16x16x32_bf16(a0, k1lo, s1, 0, 0, 0);
    s1 = __builtin_amdgcn_mfma_f32_16x16x32_bf16(a1, k1hi, s1, 0, 0, 0);
    float mk0 = mask[b * KVL + kv0 + l];
    float mk1 = mask[b * KVL + kv0 + 16 + l];
    int c0 = kv0 + l, c1 = kv0 + 16 + l;
#pragma unroll
    for (int r = 0; r < 4; r++) {
      int lim = CL + qbase + quad * 4 + r;          // absolute causal frontier
      float v0 = (c0 <= lim) ? s0[r] * 0.125f + mk0 : -INFINITY;
      float v1 = (c1 <= lim) ? s1[r] * 0.125f + mk1 : -INFINITY;
      float t = fmaxf(v0, v1);
      t = fmaxf(t, __shfl_xor(t, 1, 16));
      t = fmaxf(t, __shfl_xor(t, 2, 16));
      t = fmaxf(t, __shfl_xor(t, 4, 16));
      t = fmaxf(t, __shfl_xor(t, 8, 16));
      float mnew = fmaxf(mr[r], t);
      float alpha = (mnew == -INFINITY) ? 0.f : __expf(mr[r] - mnew);
      float p0 = (v0 == -INFINITY) ? 0.f : __expf(v0 - mnew);
      float p1 = (v1 == -INFINITY) ? 0.f : __expf(v1 - mnew);
      float rs = p0 + p1;
      rs += __shfl_xor(rs, 1, 16);
      rs += __shfl_xor(rs, 2, 16);
      rs += __shfl_xor(rs, 4, 16);
      rs += __shfl_xor(rs, 8, 16);
      lr[r] = lr[r] * alpha + rs;
      mr[r] = mnew;
      o0[r] *= alpha; o1[r] *= alpha; o2[r] *= alpha; o3[r] *= alpha;
      Pl[wave][(quad * 4 + r) * 40 + l]      = f2b(p0);
      Pl[wave][(quad * 4 + r) * 40 + 16 + l] = f2b(p1);
    }
    __syncthreads();
    // P: C-layout -> A-layout via LDS
    short8 pa = *(const short8*)&Pl[wave][l * 40 + quad * 8];
    short8 bv0, bv1, bv2, bv3;
#pragma unroll
    for (int j = 0; j < 8; j++) {
      int rr = (quad * 8 + j) * 66 + l;
      bv0[j] = (short)Vl[rr];
      bv1[j] = (short)Vl[rr + 16];
      bv2[j] = (short)Vl[rr + 32];
      bv3[j] = (short)Vl[rr + 48];
    }
    o0 = __builtin_amdgcn_mfma_f32_16x16x32_bf16(pa, bv0, o0, 0, 0, 0);
    o1 = __builtin_amdgcn_mfma_f32_16x16x32_bf16(pa, bv1, o1, 0, 0, 0);
    o2 = __builtin_amdgcn_mfma_f32_16x16x32_bf16(pa, bv2, o2, 0, 0, 0);
    o3 = __builtin_amdgcn_mfma_f32_16x16x32_bf16(pa, bv3, o3, 0, 0, 0);
    __syncthreads();
  }
#pragma unroll
  for (int r = 0; r < 4; r++) {
    float inv = 1.0f / lr[r];
    size_t base = (size_t)(b * QL + qbase + quad * 4 + r) * EMB + h * HD + l;
    Cb[base]      = f2b(o0[r] * inv);
    Cb[base + 16] = f2b(o1[r] * inv);
    Cb[base + 32] = f2b(o2[r] * inv);
    Cb[base + 48] = f2b(o3[r] * inv);
  }
}

extern "C" void kernel_launch(void* const* d_in, const int* in_sizes, int n_in,
                              void* d_out, int out_size, void* d_ws, size_t ws_size,
                              hipStream_t stream) {
  const float* hid  = (const float*)d_in[0];
  const float* mask = (const float*)d_in[1];
  const float* kc   = (const float*)d_in[2];
  const float* vc   = (const float*)d_in[3];
  const float* Wq   = (const float*)d_in[4];
  const float* bq   = (const float*)d_in[5];
  const float* Wk   = (const float*)d_in[6];
  const float* bk   = (const float*)d_in[7];
  const float* Wv   = (const float*)d_in[8];
  const float* bv   = (const float*)d_in[9];
  const float* Wo   = (const float*)d_in[10];
  const float* bo   = (const float*)d_in[11];

  float* out_f = (float*)d_out;
  float* kf = out_f + (size_t)BZv * QL * EMB;
  float* vf = kf + (size_t)BZv * KVL * EMB;

  char* p = (char*)d_ws;
  unsigned short* Xb  = (unsigned short*)p; p += (size_t)BZv * QL * EMB * 2;
  unsigned short* Wqb = (unsigned short*)p; p += (size_t)EMB * EMB * 2;
  unsigned short* Wkb = (unsigned short*)p; p += (size_t)EMB * EMB * 2;
  unsigned short* Wvb = (unsigned short*)p; p += (size_t)EMB * EMB * 2;
  unsigned short* Wob = (unsigned short*)p; p += (size_t)EMB * EMB * 2;
  unsigned short* Qb  = (unsigned short*)p; p += (size_t)BZv * QL * EMB * 2;
  unsigned short* Kb  = (unsigned short*)p; p += (size_t)BZv * KVL * EMB * 2;
  unsigned short* Vb  = (unsigned short*)p; p += (size_t)BZv * KVL * EMB * 2;
  unsigned short* Cb  = (unsigned short*)p; p += (size_t)BZv * QL * EMB * 2;

  prep_kernel<<<2048, 256, 0, stream>>>(hid, Wq, Wk, Wv, Wo, kc, vc,
                                        Xb, Wqb, Wkb, Wvb, Wob, Kb, Vb, kf, vf);
  dim3 g(EMB / 64, (BZv * QL) / 64);   // (16, 32)
  proj_gemm<<<g, 256, 0, stream>>>(Xb, Wqb, bq, Qb, (float*)nullptr, 0);
  proj_gemm<<<g, 256, 0, stream>>>(Xb, Wkb, bk, Kb, kf, 1);
  proj_gemm<<<g, 256, 0, stream>>>(Xb, Wvb, bv, Vb, vf, 1);
  attn_kernel<<<dim3(QL / 64, NH, BZv), 256, 0, stream>>>(Qb, Kb, Vb, mask, Cb);
  proj_gemm<<<g, 256, 0, stream>>>(Cb, Wob, bo, (unsigned short*)nullptr, out_f, 0);
}

// Round 2
// 299.282 us; speedup vs baseline: 1.4591x; 1.4591x over previous
//
#include <hip/hip_runtime.h>
#include <stdint.h>

#define BZv 4
#define QL 512
#define CL 1536
#define KVL 2048
#define EMB 1024
#define NH 16
#define HD 64

typedef __attribute__((ext_vector_type(8))) short short8;
typedef __attribute__((ext_vector_type(4))) float floatx4;

__device__ __forceinline__ unsigned short f2b(float f) {
  union { float f; unsigned int u; } v; v.f = f;
  return (unsigned short)((v.u + 0x7FFFu + ((v.u >> 16) & 1u)) >> 16);
}

__device__ __forceinline__ void gload_lds16(const void* g, void* l) {
  __builtin_amdgcn_global_load_lds(
      (const __attribute__((address_space(1))) unsigned char*)g,
      (__attribute__((address_space(3))) unsigned char*)l, 16, 0, 0);
}

// ---------------- prep: fp32->bf16 conversions + cache copies ----------------
__global__ __launch_bounds__(256) void prep_kernel(
    const float* __restrict__ hid, const float* __restrict__ Wq, const float* __restrict__ Wk,
    const float* __restrict__ Wv, const float* __restrict__ Wo,
    const float* __restrict__ kc, const float* __restrict__ vc,
    unsigned short* __restrict__ Xb, unsigned short* __restrict__ Wqb, unsigned short* __restrict__ Wkb,
    unsigned short* __restrict__ Wvb, unsigned short* __restrict__ Wob,
    unsigned short* __restrict__ Kb, unsigned short* __restrict__ Vb,
    float* __restrict__ kf, float* __restrict__ vf)
{
  const long HID4 = (long)BZv * QL * EMB / 4;
  const long W4   = (long)EMB * EMB / 4;
  const long C4   = (long)BZv * CL * EMB / 4;
  const long t0 = HID4, t1 = t0 + W4, t2 = t1 + W4, t3 = t2 + W4, t4 = t3 + W4;
  const long t5 = t4 + C4, total = t5 + C4;
  for (long i = (long)blockIdx.x * blockDim.x + threadIdx.x; i < total;
       i += (long)gridDim.x * blockDim.x) {
    if (i < t4) {
      const float* src; unsigned short* dst; long j;
      if (i < t0)      { src = hid; dst = Xb;  j = i; }
      else if (i < t1) { src = Wq;  dst = Wqb; j = i - t0; }
      else if (i < t2) { src = Wk;  dst = Wkb; j = i - t1; }
      else if (i < t3) { src = Wv;  dst = Wvb; j = i - t2; }
      else             { src = Wo;  dst = Wob; j = i - t3; }
      float4 v = ((const float4*)src)[j];
      ushort4 o; o.x = f2b(v.x); o.y = f2b(v.y); o.z = f2b(v.z); o.w = f2b(v.w);
      ((ushort4*)dst)[j] = o;
    } else {
      bool isV = (i >= t5);
      long j = i - (isV ? t5 : t4);
      const float* src = isV ? vc : kc;
      float4 v = ((const float4*)src)[j];
      long e4 = j * 4;
      int b = (int)(e4 / ((long)CL * EMB));
      long rem = e4 - (long)b * CL * EMB;
      long doff = (long)b * KVL * EMB + rem;
      float* of = isV ? vf : kf;
      unsigned short* ob = isV ? Vb : Kb;
      *((float4*)(of + doff)) = v;
      ushort4 o; o.x = f2b(v.x); o.y = f2b(v.y); o.z = f2b(v.z); o.w = f2b(v.w);
      *((ushort4*)(ob + doff)) = o;
    }
  }
}

// ---------------- fused QKV GEMM: [2048x1024] @ {Wq,Wk,Wv}^T, 128x128 tiles --------
// grid (24,16): blockIdx.x selects matrix (x>>3) and 128-col tile (x&7).
__global__ __launch_bounds__(256) void qkv_gemm(
    const unsigned short* __restrict__ Xb,
    const unsigned short* __restrict__ Wqb, const unsigned short* __restrict__ Wkb,
    const unsigned short* __restrict__ Wvb,
    const float* __restrict__ bq, const float* __restrict__ bk, const float* __restrict__ bv,
    unsigned short* __restrict__ Qb, unsigned short* __restrict__ Kb, unsigned short* __restrict__ Vb,
    float* __restrict__ kf, float* __restrict__ vf)
{
  __shared__ unsigned short At[128 * 32];
  __shared__ unsigned short Bt[128 * 32];
  const int tid = threadIdx.x, lane = tid & 63, wave = tid >> 6;
  const int quad = lane >> 4, l = lane & 15;
  const int mat = blockIdx.x >> 3;
  const int ncol = (blockIdx.x & 7) * 128;
  const int mbase = blockIdx.y * 128;
  const unsigned short* W = (mat == 0) ? Wqb : (mat == 1) ? Wkb : Wvb;
  const float* bias = (mat == 0) ? bq : (mat == 1) ? bk : bv;
  const int srow = tid >> 2, slds = tid & 3;
  const int rh = (wave & 1) * 64, ch = (wave >> 1) * 64;

  floatx4 zero = {0.f, 0.f, 0.f, 0.f};
  floatx4 acc[4][4];
#pragma unroll
  for (int i = 0; i < 4; i++)
#pragma unroll
    for (int j = 0; j < 4; j++) acc[i][j] = zero;

  for (int k0 = 0; k0 < EMB; k0 += 32) {
    __syncthreads();
#pragma unroll
    for (int s = 0; s < 2; s++) {
      int row = s * 64 + srow;
      int gc = slds ^ (row & 3);
      gload_lds16(Xb + (size_t)(mbase + row) * EMB + k0 + gc * 8, &At[row * 32 + slds * 8]);
    }
#pragma unroll
    for (int s = 0; s < 2; s++) {
      int row = s * 64 + srow;
      int gc = slds ^ (row & 3);
      gload_lds16(W + (size_t)(ncol + row) * EMB + k0 + gc * 8, &Bt[row * 32 + slds * 8]);
    }
    __syncthreads();
    short8 af[4], bfr[4];
#pragma unroll
    for (int rt = 0; rt < 4; rt++) {
      int row = rh + rt * 16 + l;
      af[rt] = *(const short8*)&At[row * 32 + ((quad ^ (row & 3)) * 8)];
    }
#pragma unroll
    for (int ct = 0; ct < 4; ct++) {
      int row = ch + ct * 16 + l;
      bfr[ct] = *(const short8*)&Bt[row * 32 + ((quad ^ (row & 3)) * 8)];
    }
#pragma unroll
    for (int rt = 0; rt < 4; rt++)
#pragma unroll
      for (int ct = 0; ct < 4; ct++)
        acc[rt][ct] = __builtin_amdgcn_mfma_f32_16x16x32_bf16(af[rt], bfr[ct], acc[rt][ct], 0, 0, 0);
  }

#pragma unroll
  for (int ct = 0; ct < 4; ct++) {
    int col = ncol + ch + ct * 16 + l;
    float bb = bias[col];
#pragma unroll
    for (int rt = 0; rt < 4; rt++)
#pragma unroll
      for (int r = 0; r < 4; r++) {
        int m = mbase + rh + rt * 16 + quad * 4 + r;
        float val = acc[rt][ct][r] + bb;
        if (mat == 0) {
          Qb[(size_t)m * EMB + col] = f2b(val);
        } else {
          size_t a = ((size_t)(m >> 9) * KVL + CL + (m & 511)) * EMB + col;
          if (mat == 1) { Kb[a] = f2b(val); kf[a] = val; }
          else          { Vb[a] = f2b(val); vf[a] = val; }
        }
      }
  }
}

// ---------------- O-proj GEMM: [2048x1024] @ Wo^T, 64x128 tiles, grid (8,32) -------
__global__ __launch_bounds__(256) void oproj_gemm(
    const unsigned short* __restrict__ A, const unsigned short* __restrict__ W,
    const float* __restrict__ bias, float* __restrict__ out)
{
  __shared__ unsigned short At[64 * 32];
  __shared__ unsigned short Bt[128 * 32];
  const int tid = threadIdx.x, lane = tid & 63, wave = tid >> 6;
  const int quad = lane >> 4, l = lane & 15;
  const int ncol = blockIdx.x * 128;
  const int mbase = blockIdx.y * 64;
  const int srow = tid >> 2, slds = tid & 3;
  const int rh = (wave & 1) * 32, ch = (wave >> 1) * 64;

  floatx4 zero = {0.f, 0.f, 0.f, 0.f};
  floatx4 acc[2][4];
#pragma unroll
  for (int i = 0; i < 2; i++)
#pragma unroll
    for (int j = 0; j < 4; j++) acc[i][j] = zero;

  for (int k0 = 0; k0 < EMB; k0 += 32) {
    __syncthreads();
    {
      int row = srow;
      int gc = slds ^ (row & 3);
      gload_lds16(A + (size_t)(mbase + row) * EMB + k0 + gc * 8, &At[row * 32 + slds * 8]);
    }
#pragma unroll
    for (int s = 0; s < 2; s++) {
      int row = s * 64 + srow;
      int gc = slds ^ (row & 3);
      gload_lds16(W + (size_t)(ncol + row) * EMB + k0 + gc * 8, &Bt[row * 32 + slds * 8]);
    }
    __syncthreads();
    short8 af[2], bfr[4];
#pragma unroll
    for (int rt = 0; rt < 2; rt++) {
      int row = rh + rt * 16 + l;
      af[rt] = *(const short8*)&At[row * 32 + ((quad ^ (row & 3)) * 8)];
    }
#pragma unroll
    for (int ct = 0; ct < 4; ct++) {
      int row = ch + ct * 16 + l;
      bfr[ct] = *(const short8*)&Bt[row * 32 + ((quad ^ (row & 3)) * 8)];
    }
#pragma unroll
    for (int rt = 0; rt < 2; rt++)
#pragma unroll
      for (int ct = 0; ct < 4; ct++)
        acc[rt][ct] = __builtin_amdgcn_mfma_f32_16x16x32_bf16(af[rt], bfr[ct], acc[rt][ct], 0, 0, 0);
  }

#pragma unroll
  for (int ct = 0; ct < 4; ct++) {
    int col = ncol + ch + ct * 16 + l;
    float bb = bias[col];
#pragma unroll
    for (int rt = 0; rt < 2; rt++)
#pragma unroll
      for (int r = 0; r < 4; r++) {
        int m = mbase + rh + rt * 16 + quad * 4 + r;
        out[(size_t)m * EMB + col] = acc[rt][ct][r] + bb;
      }
  }
}

// ---------------- flash attention v2: kv tile 64, K reg-prefetch, V^T in LDS -------
// grid (QL/64, NH, BZ), block 256 = 4 waves; each wave 16 q rows.
__global__ __launch_bounds__(256) void attn_kernel(
    const unsigned short* __restrict__ Qb, const unsigned short* __restrict__ Kb,
    const unsigned short* __restrict__ Vb, const float* __restrict__ mask,
    unsigned short* __restrict__ Cb)
{
  __shared__ unsigned short Vt[2][64 * 72];   // [buf][d*72 + kv], stride 72 (2-way-free b128)
  __shared__ unsigned short Pl[4][16 * 72];   // per-wave P tile [qrow*72 + kv]
  const int b = blockIdx.z, h = blockIdx.y, qt = blockIdx.x;
  const int tid = threadIdx.x, lane = tid & 63, wave = tid >> 6;
  const int quad = lane >> 4, l = lane & 15;
  const int qbase = qt * 64 + wave * 16;

  const unsigned short* qp = Qb + (size_t)(b * QL + qbase + l) * EMB + h * HD + quad * 8;
  const short8 a0 = *(const short8*)qp;
  const short8 a1 = *(const short8*)(qp + 32);

  floatx4 zero = {0.f, 0.f, 0.f, 0.f};
  floatx4 o[4];
  float mr[4], lrp[4];
#pragma unroll
  for (int c = 0; c < 4; c++) o[c] = zero;
#pragma unroll
  for (int r = 0; r < 4; r++) { mr[r] = -INFINITY; lrp[r] = 0.f; }

  const int kv_end = CL + qt * 64 + 64;
  // V staging role: thread -> kv pair (2 rows) x 8 d-values
  const int vp = tid & 31, vg = tid >> 5;
  const unsigned short* vsrc = Vb + (size_t)(b * KVL) * EMB + h * HD + vg * 8;
  const unsigned short* kbase = Kb + (size_t)(b * KVL) * EMB + h * HD + quad * 8;

  // prologue: tile 0
  uint4 va = *(const uint4*)(vsrc + (size_t)(2 * vp) * EMB);
  uint4 vb = *(const uint4*)(vsrc + (size_t)(2 * vp + 1) * EMB);
  short8 kc[8];
#pragma unroll
  for (int c = 0; c < 4; c++) {
    const unsigned short* kp = kbase + (size_t)(c * 16 + l) * EMB;
    kc[2 * c] = *(const short8*)kp;
    kc[2 * c + 1] = *(const short8*)(kp + 32);
  }
  {
    const unsigned short* pa = (const unsigned short*)&va;
    const unsigned short* pb = (const unsigned short*)&vb;
#pragma unroll
    for (int j = 0; j < 8; j++) {
      ushort2 t; t.x = pa[j]; t.y = pb[j];
      *(ushort2*)&Vt[0][(vg * 8 + j) * 72 + 2 * vp] = t;
    }
  }
  __syncthreads();

  int cur = 0;
  for (int kv0 = 0; kv0 < kv_end; kv0 += 64) {
    const bool more = (kv0 + 64 < kv_end);
    uint4 vna, vnb;
    short8 kn[8];
    if (more) {
      const unsigned short* vs = vsrc + (size_t)(kv0 + 64 + 2 * vp) * EMB;
      vna = *(const uint4*)vs;
      vnb = *(const uint4*)(vs + EMB);
#pragma unroll
      for (int c = 0; c < 4; c++) {
        const unsigned short* kp = kbase + (size_t)(kv0 + 64 + c * 16 + l) * EMB;
        kn[2 * c] = *(const short8*)kp;
        kn[2 * c + 1] = *(const short8*)(kp + 32);
      }
    }
    // S = Q K^T (16 q x 64 kv)
    floatx4 s[4];
#pragma unroll
    for (int c = 0; c < 4; c++) {
      s[c] = zero;
      s[c] = __builtin_amdgcn_mfma_f32_16x16x32_bf16(a0, kc[2 * c], s[c], 0, 0, 0);
      s[c] = __builtin_amdgcn_mfma_f32_16x16x32_bf16(a1, kc[2 * c + 1], s[c], 0, 0, 0);
    }
    float mk[4];
#pragma unroll
    for (int c = 0; c < 4; c++) mk[c] = mask[b * KVL + kv0 + c * 16 + l];
#pragma unroll
    for (int r = 0; r < 4; r++) {
      const int lim = CL + qbase + quad * 4 + r;
      float v[4];
#pragma unroll
      for (int c = 0; c < 4; c++) {
        int col = kv0 + c * 16 + l;
        v[c] = (col <= lim) ? s[c][r] * 0.125f + mk[c] : -INFINITY;
      }
      float t = fmaxf(fmaxf(v[0], v[1]), fmaxf(v[2], v[3]));
      t = fmaxf(t, __shfl_xor(t, 1, 16));
      t = fmaxf(t, __shfl_xor(t, 2, 16));
      t = fmaxf(t, __shfl_xor(t, 4, 16));
      t = fmaxf(t, __shfl_xor(t, 8, 16));
      float mnew = fmaxf(mr[r], t);
      float alpha = __expf(mr[r] - mnew);
      mr[r] = mnew;
      float ps = 0.f;
#pragma unroll
      for (int c = 0; c < 4; c++) {
        float p = (v[c] == -INFINITY) ? 0.f : __expf(v[c] - mnew);
        ps += p;
        Pl[wave][(quad * 4 + r) * 72 + c * 16 + l] = f2b(p);
      }
      lrp[r] = lrp[r] * alpha + ps;
#pragma unroll
      for (int c = 0; c < 4; c++) o[c][r] *= alpha;
    }
    asm volatile("s_waitcnt lgkmcnt(0)" ::: "memory");
    short8 pa0 = *(const short8*)&Pl[wave][l * 72 + quad * 8];
    short8 pa1 = *(const short8*)&Pl[wave][l * 72 + 32 + quad * 8];
#pragma unroll
    for (int c = 0; c < 4; c++) {
      short8 b0 = *(const short8*)&Vt[cur][(c * 16 + l) * 72 + quad * 8];
      short8 b1 = *(const short8*)&Vt[cur][(c * 16 + l) * 72 + 32 + quad * 8];
      o[c] = __builtin_amdgcn_mfma_f32_16x16x32_bf16(pa0, b0, o[c], 0, 0, 0);
      o[c] = __builtin_amdgcn_mfma_f32_16x16x32_bf16(pa1, b1, o[c], 0, 0, 0);
    }
    if (more) {
      const unsigned short* pa = (const unsigned short*)&vna;
      const unsigned short* pb = (const unsigned short*)&vnb;
#pragma unroll
      for (int j = 0; j < 8; j++) {
        ushort2 t; t.x = pa[j]; t.y = pb[j];
        *(ushort2*)&Vt[cur ^ 1][(vg * 8 + j) * 72 + 2 * vp] = t;
      }
#pragma unroll
      for (int i = 0; i < 8; i++) kc[i] = kn[i];
    }
    __syncthreads();
    cur ^= 1;
  }

#pragma unroll
  for (int r = 0; r < 4; r++) {
    float s = lrp[r];
    s += __shfl_xor(s, 1, 16);
    s += __shfl_xor(s, 2, 16);
    s += __shfl_xor(s, 4, 16);
    s += __shfl_xor(s, 8, 16);
    float inv = 1.0f / s;
    size_t base = (size_t)(b * QL + qbase + quad * 4 + r) * EMB + h * HD + l;
#pragma unroll
    for (int c = 0; c < 4; c++) Cb[base + c * 16] = f2b(o[c][r] * inv);
  }
}

extern "C" void kernel_launch(void* const* d_in, const int* in_sizes, int n_in,
                              void* d_out, int out_size, void* d_ws, size_t ws_size,
                              hipStream_t stream) {
  const float* hid  = (const float*)d_in[0];
  const float* mask = (const float*)d_in[1];
  const float* kc   = (const float*)d_in[2];
  const float* vc   = (const float*)d_in[3];
  const float* Wq   = (const float*)d_in[4];
  const float* bq   = (const float*)d_in[5];
  const float* Wk   = (const float*)d_in[6];
  const float* bk   = (const float*)d_in[7];
  const float* Wv   = (const float*)d_in[8];
  const float* bv   = (const float*)d_in[9];
  const float* Wo   = (const float*)d_in[10];
  const float* bo   = (const float*)d_in[11];

  float* out_f = (float*)d_out;
  float* kf = out_f + (size_t)BZv * QL * EMB;
  float* vf = kf + (size_t)BZv * KVL * EMB;

  char* p = (char*)d_ws;
  unsigned short* Xb  = (unsigned short*)p; p += (size_t)BZv * QL * EMB * 2;
  unsigned short* Wqb = (unsigned short*)p; p += (size_t)EMB * EMB * 2;
  unsigned short* Wkb = (unsigned short*)p; p += (size_t)EMB * EMB * 2;
  unsigned short* Wvb = (unsigned short*)p; p += (size_t)EMB * EMB * 2;
  unsigned short* Wob = (unsigned short*)p; p += (size_t)EMB * EMB * 2;
  unsigned short* Qb  = (unsigned short*)p; p += (size_t)BZv * QL * EMB * 2;
  unsigned short* Kb  = (unsigned short*)p; p += (size_t)BZv * KVL * EMB * 2;
  unsigned short* Vb  = (unsigned short*)p; p += (size_t)BZv * KVL * EMB * 2;
  unsigned short* Cb  = (unsigned short*)p; p += (size_t)BZv * QL * EMB * 2;

  prep_kernel<<<2048, 256, 0, stream>>>(hid, Wq, Wk, Wv, Wo, kc, vc,
                                        Xb, Wqb, Wkb, Wvb, Wob, Kb, Vb, kf, vf);
  qkv_gemm<<<dim3(24, 16), 256, 0, stream>>>(Xb, Wqb, Wkb, Wvb, bq, bk, bv,
                                             Qb, Kb, Vb, kf, vf);
  attn_kernel<<<dim3(QL / 64, NH, BZv), 256, 0, stream>>>(Qb, Kb, Vb, mask, Cb);
  oproj_gemm<<<dim3(8, 32), 256, 0, stream>>>(Cb, Wob, bo, out_f);
}

// Round 3
// 287.848 us; speedup vs baseline: 1.5170x; 1.0397x over previous
//
#include <hip/hip_runtime.h>
#include <hip/hip_bf16.h>
#include <stdint.h>

#define BZv 4
#define QL 512
#define CL 1536
#define KVL 2048
#define EMB 1024
#define NH 16
#define HD 64
#define QSCALE 0.18033688011112042f  /* 0.125 * log2(e) */

typedef __attribute__((ext_vector_type(8))) short short8;
typedef __attribute__((ext_vector_type(4))) float floatx4;

__device__ __forceinline__ unsigned short f2b(float f) {
  union { float f; unsigned int u; } v; v.f = f;
  return (unsigned short)((v.u + 0x7FFFu + ((v.u >> 16) & 1u)) >> 16);
}

__device__ __forceinline__ ushort2 pk2(float a, float b) {
  union { __hip_bfloat162 h; ushort2 u; } c;
  c.h = __float22bfloat162_rn(make_float2(a, b));
  return c.u;
}

#if __has_builtin(__builtin_amdgcn_exp2f)
#define EXP2F(x) __builtin_amdgcn_exp2f(x)
#else
#define EXP2F(x) exp2f(x)
#endif

__device__ __forceinline__ void gload_lds16(const void* g, void* l) {
  __builtin_amdgcn_global_load_lds(
      (const __attribute__((address_space(1))) unsigned char*)g,
      (__attribute__((address_space(3))) unsigned char*)l, 16, 0, 0);
}

// ---------------- prep: fp32->bf16 + cache copies + w = exp(mask) ----------------
__global__ __launch_bounds__(256) void prep_kernel(
    const float* __restrict__ hid, const float* __restrict__ Wq, const float* __restrict__ Wk,
    const float* __restrict__ Wv, const float* __restrict__ Wo,
    const float* __restrict__ kc, const float* __restrict__ vc, const float* __restrict__ msk,
    unsigned short* __restrict__ Xb, unsigned short* __restrict__ Wqb, unsigned short* __restrict__ Wkb,
    unsigned short* __restrict__ Wvb, unsigned short* __restrict__ Wob,
    unsigned short* __restrict__ Kb, unsigned short* __restrict__ Vb,
    float* __restrict__ kf, float* __restrict__ vf, unsigned short* __restrict__ wb)
{
  const long HID4 = (long)BZv * QL * EMB / 4;
  const long W4   = (long)EMB * EMB / 4;
  const long C4   = (long)BZv * CL * EMB / 4;
  const long t0 = HID4, t1 = t0 + W4, t2 = t1 + W4, t3 = t2 + W4, t4 = t3 + W4;
  const long t5 = t4 + C4, t6 = t5 + C4;
  const long total = t6 + (long)BZv * KVL / 4;
  for (long i = (long)blockIdx.x * blockDim.x + threadIdx.x; i < total;
       i += (long)gridDim.x * blockDim.x) {
    if (i < t4) {
      const float* src; unsigned short* dst; long j;
      if (i < t0)      { src = hid; dst = Xb;  j = i; }
      else if (i < t1) { src = Wq;  dst = Wqb; j = i - t0; }
      else if (i < t2) { src = Wk;  dst = Wkb; j = i - t1; }
      else if (i < t3) { src = Wv;  dst = Wvb; j = i - t2; }
      else             { src = Wo;  dst = Wob; j = i - t3; }
      float4 v = ((const float4*)src)[j];
      ushort4 o; o.x = f2b(v.x); o.y = f2b(v.y); o.z = f2b(v.z); o.w = f2b(v.w);
      ((ushort4*)dst)[j] = o;
    } else if (i < t6) {
      bool isV = (i >= t5);
      long j = i - (isV ? t5 : t4);
      const float* src = isV ? vc : kc;
      float4 v = ((const float4*)src)[j];
      long e4 = j * 4;
      int b = (int)(e4 / ((long)CL * EMB));
      long rem = e4 - (long)b * CL * EMB;
      long doff = (long)b * KVL * EMB + rem;
      if (isV) {
        *((float4*)(vf + doff)) = v;
        int row = (int)(rem >> 10);                 // EMB = 1024
        float w = __expf(msk[b * KVL + row]);
        ushort4 o; o.x = f2b(v.x * w); o.y = f2b(v.y * w);
        o.z = f2b(v.z * w); o.w = f2b(v.w * w);
        *((ushort4*)(Vb + doff)) = o;
      } else {
        *((float4*)(kf + doff)) = v;
        ushort4 o; o.x = f2b(v.x); o.y = f2b(v.y); o.z = f2b(v.z); o.w = f2b(v.w);
        *((ushort4*)(Kb + doff)) = o;
      }
    } else {
      long j = i - t6;                              // over BZv*KVL/4
      float4 m4 = ((const float4*)msk)[j];
      ushort4 o;
      o.x = f2b(__expf(m4.x)); o.y = f2b(__expf(m4.y));
      o.z = f2b(__expf(m4.z)); o.w = f2b(__expf(m4.w));
      ((ushort4*)wb)[j] = o;
    }
  }
}

// ---------------- fused QKV GEMM: 128x64 tiles, grid (48,16) ----------------
__global__ __launch_bounds__(256) void qkv_gemm(
    const unsigned short* __restrict__ Xb,
    const unsigned short* __restrict__ Wqb, const unsigned short* __restrict__ Wkb,
    const unsigned short* __restrict__ Wvb,
    const float* __restrict__ bq, const float* __restrict__ bk, const float* __restrict__ bv,
    const float* __restrict__ msk,
    unsigned short* __restrict__ Qb, unsigned short* __restrict__ Kb, unsigned short* __restrict__ Vb,
    float* __restrict__ kf, float* __restrict__ vf)
{
  __shared__ unsigned short At[128 * 32];
  __shared__ unsigned short Bt[64 * 32];
  const int tid = threadIdx.x, lane = tid & 63, wave = tid >> 6;
  const int quad = lane >> 4, l = lane & 15;
  const int mat = blockIdx.x >> 4;
  const int ncol = (blockIdx.x & 15) * 64;
  const int mbase = blockIdx.y * 128;
  const unsigned short* W = (mat == 0) ? Wqb : (mat == 1) ? Wkb : Wvb;
  const float* bias = (mat == 0) ? bq : (mat == 1) ? bk : bv;
  const int srow = tid >> 2, slds = tid & 3;
  const int rh = wave * 32;

  floatx4 zero = {0.f, 0.f, 0.f, 0.f};
  floatx4 acc[2][4];
#pragma unroll
  for (int i = 0; i < 2; i++)
#pragma unroll
    for (int j = 0; j < 4; j++) acc[i][j] = zero;

  for (int k0 = 0; k0 < EMB; k0 += 32) {
    __syncthreads();
#pragma unroll
    for (int s = 0; s < 2; s++) {
      int row = s * 64 + srow;
      int gc = slds ^ (row & 3);
      gload_lds16(Xb + (size_t)(mbase + row) * EMB + k0 + gc * 8, &At[row * 32 + slds * 8]);
    }
    {
      int row = srow;
      int gc = slds ^ (row & 3);
      gload_lds16(W + (size_t)(ncol + row) * EMB + k0 + gc * 8, &Bt[row * 32 + slds * 8]);
    }
    __syncthreads();
    short8 af[2], bfr[4];
#pragma unroll
    for (int rt = 0; rt < 2; rt++) {
      int row = rh + rt * 16 + l;
      af[rt] = *(const short8*)&At[row * 32 + ((quad ^ (row & 3)) * 8)];
    }
#pragma unroll
    for (int ct = 0; ct < 4; ct++) {
      int row = ct * 16 + l;
      bfr[ct] = *(const short8*)&Bt[row * 32 + ((quad ^ (row & 3)) * 8)];
    }
#pragma unroll
    for (int rt = 0; rt < 2; rt++)
#pragma unroll
      for (int ct = 0; ct < 4; ct++)
        acc[rt][ct] = __builtin_amdgcn_mfma_f32_16x16x32_bf16(af[rt], bfr[ct], acc[rt][ct], 0, 0, 0);
  }

#pragma unroll
  for (int ct = 0; ct < 4; ct++) {
    int col = ncol + ct * 16 + l;
    float bb = bias[col];
#pragma unroll
    for (int rt = 0; rt < 2; rt++)
#pragma unroll
      for (int r = 0; r < 4; r++) {
        int m = mbase + rh + rt * 16 + quad * 4 + r;
        float val = acc[rt][ct][r] + bb;
        if (mat == 0) {
          Qb[(size_t)m * EMB + col] = f2b(val * QSCALE);
        } else {
          size_t a = ((size_t)(m >> 9) * KVL + CL + (m & 511)) * EMB + col;
          if (mat == 1) { Kb[a] = f2b(val); kf[a] = val; }
          else {
            float w = __expf(msk[(m >> 9) * KVL + CL + (m & 511)]);
            Vb[a] = f2b(val * w); vf[a] = val;
          }
        }
      }
  }
}

// ---------------- O-proj GEMM: 64x64 tiles, grid (16,32) ----------------
__global__ __launch_bounds__(256) void oproj_gemm(
    const unsigned short* __restrict__ A, const unsigned short* __restrict__ W,
    const float* __restrict__ bias, float* __restrict__ out)
{
  __shared__ unsigned short At[64 * 32];
  __shared__ unsigned short Bt[64 * 32];
  const int tid = threadIdx.x, lane = tid & 63, wave = tid >> 6;
  const int quad = lane >> 4, l = lane & 15;
  const int ncol = blockIdx.x * 64;
  const int mbase = blockIdx.y * 64;
  const int srow = tid >> 2, slds = tid & 3;
  const int rh = (wave & 1) * 32, ch = (wave >> 1) * 32;

  floatx4 zero = {0.f, 0.f, 0.f, 0.f};
  floatx4 acc[2][2];
#pragma unroll
  for (int i = 0; i < 2; i++)
#pragma unroll
    for (int j = 0; j < 2; j++) acc[i][j] = zero;

  for (int k0 = 0; k0 < EMB; k0 += 32) {
    __syncthreads();
    {
      int gc = slds ^ (srow & 3);
      gload_lds16(A + (size_t)(mbase + srow) * EMB + k0 + gc * 8, &At[srow * 32 + slds * 8]);
      gload_lds16(W + (size_t)(ncol + srow) * EMB + k0 + gc * 8, &Bt[srow * 32 + slds * 8]);
    }
    __syncthreads();
    short8 af[2], bfr[2];
#pragma unroll
    for (int rt = 0; rt < 2; rt++) {
      int row = rh + rt * 16 + l;
      af[rt] = *(const short8*)&At[row * 32 + ((quad ^ (row & 3)) * 8)];
    }
#pragma unroll
    for (int ct = 0; ct < 2; ct++) {
      int row = ch + ct * 16 + l;
      bfr[ct] = *(const short8*)&Bt[row * 32 + ((quad ^ (row & 3)) * 8)];
    }
#pragma unroll
    for (int rt = 0; rt < 2; rt++)
#pragma unroll
      for (int ct = 0; ct < 2; ct++)
        acc[rt][ct] = __builtin_amdgcn_mfma_f32_16x16x32_bf16(af[rt], bfr[ct], acc[rt][ct], 0, 0, 0);
  }

#pragma unroll
  for (int ct = 0; ct < 2; ct++) {
    int col = ncol + ch + ct * 16 + l;
    float bb = bias[col];
#pragma unroll
    for (int rt = 0; rt < 2; rt++)
#pragma unroll
      for (int r = 0; r < 4; r++) {
        int m = mbase + rh + rt * 16 + quad * 4 + r;
        out[(size_t)m * EMB + col] = acc[rt][ct][r] + bb;
      }
  }
}

// ---------------- flash attention v3: S^T layout, per-lane softmax state -------
// 1D grid 512: id = qt*64 + (b*16+h)  (same (b,h) -> same XCD under %8 round-robin)
__global__ __launch_bounds__(256) void attn_kernel(
    const unsigned short* __restrict__ Qb, const unsigned short* __restrict__ Kb,
    const unsigned short* __restrict__ Vb, const unsigned short* __restrict__ wb,
    unsigned short* __restrict__ Cb)
{
  __shared__ unsigned short Vt[2][66 * 72];   // rows 0..63 = V^T[d][kv], row 64 = w[kv]
  __shared__ unsigned short Pl[4][16 * 72];   // per-wave P~ [q][kv]
  const int id = blockIdx.x;
  const int hb = id & 63, qt = id >> 6;
  const int b = hb >> 4, h = hb & 15;
  const int tid = threadIdx.x, lane = tid & 63, wave = tid >> 6;
  const int quad = lane >> 4, l = lane & 15;
  const int qbase = qt * 64 + wave * 16;

  const unsigned short* qp = Qb + (size_t)(b * QL + qbase + l) * EMB + h * HD + quad * 8;
  const short8 bq0 = *(const short8*)qp;        // B-frag [n=q][k=d]
  const short8 bq1 = *(const short8*)(qp + 32);

  floatx4 zero = {0.f, 0.f, 0.f, 0.f};
  floatx4 o[4], o4 = zero;
#pragma unroll
  for (int c = 0; c < 4; c++) o[c] = zero;
  float mr = -INFINITY;                          // per-lane state for q = l

  const int kv_end = CL + qt * 64 + 64;
  const int vp = tid & 31, vg = tid >> 5;
  const unsigned short* vsrc = Vb + (size_t)(b * KVL) * EMB + h * HD + vg * 8;
  const unsigned short* wsrc = wb + (size_t)b * KVL + 2 * vp;
  const unsigned short* kbase = Kb + (size_t)(b * KVL) * EMB + h * HD + quad * 8;

  // prologue: stage tile 0
  uint4 va = *(const uint4*)(vsrc + (size_t)(2 * vp) * EMB);
  uint4 vbr = *(const uint4*)(vsrc + (size_t)(2 * vp + 1) * EMB);
  short8 kc[8];
#pragma unroll
  for (int c = 0; c < 4; c++) {
    const unsigned short* kp = kbase + (size_t)(c * 16 + l) * EMB;
    kc[2 * c] = *(const short8*)kp;              // A-frag [m=kv][k=d]
    kc[2 * c + 1] = *(const short8*)(kp + 32);
  }
  {
    const unsigned short* pa = (const unsigned short*)&va;
    const unsigned short* pb = (const unsigned short*)&vbr;
#pragma unroll
    for (int j = 0; j < 8; j++) {
      ushort2 t; t.x = pa[j]; t.y = pb[j];
      *(ushort2*)&Vt[0][(vg * 8 + j) * 72 + 2 * vp] = t;
    }
    if (vg == 0) *(ushort2*)&Vt[0][64 * 72 + 2 * vp] = *(const ushort2*)wsrc;
  }
  __syncthreads();

  int cur = 0;
  for (int kv0 = 0; kv0 < kv_end; kv0 += 64) {
    const bool more = (kv0 + 64 < kv_end);
    uint4 vna, vnb; ushort2 wn; short8 kn[8];
    if (more) {
      const unsigned short* vs = vsrc + (size_t)(kv0 + 64 + 2 * vp) * EMB;
      vna = *(const uint4*)vs;
      vnb = *(const uint4*)(vs + EMB);
      if (vg == 0) wn = *(const ushort2*)(wsrc + kv0 + 64);
#pragma unroll
      for (int c = 0; c < 4; c++) {
        const unsigned short* kp = kbase + (size_t)(kv0 + 64 + c * 16 + l) * EMB;
        kn[2 * c] = *(const short8*)kp;
        kn[2 * c + 1] = *(const short8*)(kp + 32);
      }
    }
    // S^T = K . Q^T : C[row=kv][col=q]
    floatx4 s[4];
#pragma unroll
    for (int c = 0; c < 4; c++) {
      s[c] = __builtin_amdgcn_mfma_f32_16x16x32_bf16(kc[2 * c], bq0, zero, 0, 0, 0);
      s[c] = __builtin_amdgcn_mfma_f32_16x16x32_bf16(kc[2 * c + 1], bq1, s[c], 0, 0, 0);
    }
    // causal mask (only near the frontier; wave-uniform branch)
    if (kv0 + 63 > CL + qbase) {
      const int lim = CL + qbase + l;
#pragma unroll
      for (int c = 0; c < 4; c++) {
        int kvb = kv0 + c * 16 + quad * 4;
#pragma unroll
        for (int r = 0; r < 4; r++)
          s[c][r] = (kvb + r <= lim) ? s[c][r] : -INFINITY;
      }
    }
    // per-lane max over 16 regs + 2 cross-quad shuffles
    float t0 = fmaxf(fmaxf(s[0][0], s[0][1]), fmaxf(s[0][2], s[0][3]));
    float t1 = fmaxf(fmaxf(s[1][0], s[1][1]), fmaxf(s[1][2], s[1][3]));
    float t2 = fmaxf(fmaxf(s[2][0], s[2][1]), fmaxf(s[2][2], s[2][3]));
    float t3 = fmaxf(fmaxf(s[3][0], s[3][1]), fmaxf(s[3][2], s[3][3]));
    float lmax = fmaxf(fmaxf(t0, t1), fmaxf(t2, t3));
    lmax = fmaxf(lmax, __shfl_xor(lmax, 16, 64));
    lmax = fmaxf(lmax, __shfl_xor(lmax, 32, 64));
    float mnew = fmaxf(mr, lmax);
    float alpha = EXP2F(mr - mnew);
    mr = mnew;
    // P~ = exp2(s - mnew), pack, write (b64, r-contiguous)
#pragma unroll
    for (int c = 0; c < 4; c++) {
      float p0 = EXP2F(s[c][0] - mnew), p1 = EXP2F(s[c][1] - mnew);
      float p2 = EXP2F(s[c][2] - mnew), p3 = EXP2F(s[c][3] - mnew);
      ushort2 lo = pk2(p0, p1), hi = pk2(p2, p3);
      ushort4 pk; pk.x = lo.x; pk.y = lo.y; pk.z = hi.x; pk.w = hi.y;
      *(ushort4*)&Pl[wave][l * 72 + c * 16 + quad * 4] = pk;
    }
#pragma unroll
    for (int c = 0; c < 4; c++)
#pragma unroll
      for (int r = 0; r < 4; r++) o[c][r] *= alpha;
#pragma unroll
    for (int r = 0; r < 4; r++) o4[r] *= alpha;
    asm volatile("s_waitcnt lgkmcnt(0)" ::: "memory");
    short8 pf0 = *(const short8*)&Pl[wave][l * 72 + quad * 8];        // B-frag [n=q][k=kv]
    short8 pf1 = *(const short8*)&Pl[wave][l * 72 + 32 + quad * 8];
    // denominator via w-row (broadcast A-frag)
    short8 vw0 = *(const short8*)&Vt[cur][64 * 72 + quad * 8];
    short8 vw1 = *(const short8*)&Vt[cur][64 * 72 + 32 + quad * 8];
    o4 = __builtin_amdgcn_mfma_f32_16x16x32_bf16(vw0, pf0, o4, 0, 0, 0);
    o4 = __builtin_amdgcn_mfma_f32_16x16x32_bf16(vw1, pf1, o4, 0, 0, 0);
#pragma unroll
    for (int c = 0; c < 4; c++) {
      short8 a0v = *(const short8*)&Vt[cur][(c * 16 + l) * 72 + quad * 8];
      short8 a1v = *(const short8*)&Vt[cur][(c * 16 + l) * 72 + 32 + quad * 8];
      o[c] = __builtin_amdgcn_mfma_f32_16x16x32_bf16(a0v, pf0, o[c], 0, 0, 0);
      o[c] = __builtin_amdgcn_mfma_f32_16x16x32_bf16(a1v, pf1, o[c], 0, 0, 0);
    }
    if (more) {
      const unsigned short* pa = (const unsigned short*)&vna;
      const unsigned short* pb = (const unsigned short*)&vnb;
#pragma unroll
      for (int j = 0; j < 8; j++) {
        ushort2 t; t.x = pa[j]; t.y = pb[j];
        *(ushort2*)&Vt[cur ^ 1][(vg * 8 + j) * 72 + 2 * vp] = t;
      }
      if (vg == 0) *(ushort2*)&Vt[cur ^ 1][64 * 72 + 2 * vp] = wn;
#pragma unroll
      for (int i = 0; i < 8; i++) kc[i] = kn[i];
    }
    __syncthreads();
    cur ^= 1;
  }

  // epilogue: O^T[d][q] -> Cb[q][h*64+d]
  float inv = 1.0f / o4[0];
  size_t qrow = (size_t)(b * QL + qbase + l) * EMB + h * HD;
#pragma unroll
  for (int c = 0; c < 4; c++)
#pragma unroll
    for (int r = 0; r < 4; r++)
      Cb[qrow + c * 16 + quad * 4 + r] = f2b(o[c][r] * inv);
}

extern "C" void kernel_launch(void* const* d_in, const int* in_sizes, int n_in,
                              void* d_out, int out_size, void* d_ws, size_t ws_size,
                              hipStream_t stream) {
  const float* hid  = (const float*)d_in[0];
  const float* mask = (const float*)d_in[1];
  const float* kc   = (const float*)d_in[2];
  const float* vc   = (const float*)d_in[3];
  const float* Wq   = (const float*)d_in[4];
  const float* bq   = (const float*)d_in[5];
  const float* Wk   = (const float*)d_in[6];
  const float* bk   = (const float*)d_in[7];
  const float* Wv   = (const float*)d_in[8];
  const float* bv   = (const float*)d_in[9];
  const float* Wo   = (const float*)d_in[10];
  const float* bo   = (const float*)d_in[11];

  float* out_f = (float*)d_out;
  float* kf = out_f + (size_t)BZv * QL * EMB;
  float* vf = kf + (size_t)BZv * KVL * EMB;

  char* p = (char*)d_ws;
  unsigned short* Xb  = (unsigned short*)p; p += (size_t)BZv * QL * EMB * 2;
  unsigned short* Wqb = (unsigned short*)p; p += (size_t)EMB * EMB * 2;
  unsigned short* Wkb = (unsigned short*)p; p += (size_t)EMB * EMB * 2;
  unsigned short* Wvb = (unsigned short*)p; p += (size_t)EMB * EMB * 2;
  unsigned short* Wob = (unsigned short*)p; p += (size_t)EMB * EMB * 2;
  unsigned short* Qb  = (unsigned short*)p; p += (size_t)BZv * QL * EMB * 2;
  unsigned short* Kb  = (unsigned short*)p; p += (size_t)BZv * KVL * EMB * 2;
  unsigned short* Vb  = (unsigned short*)p; p += (size_t)BZv * KVL * EMB * 2;
  unsigned short* Cb  = (unsigned short*)p; p += (size_t)BZv * QL * EMB * 2;
  unsigned short* wbp = (unsigned short*)p; p += (size_t)BZv * KVL * 2;

  prep_kernel<<<2048, 256, 0, stream>>>(hid, Wq, Wk, Wv, Wo, kc, vc, mask,
                                        Xb, Wqb, Wkb, Wvb, Wob, Kb, Vb, kf, vf, wbp);
  qkv_gemm<<<dim3(48, 16), 256, 0, stream>>>(Xb, Wqb, Wkb, Wvb, bq, bk, bv, mask,
                                             Qb, Kb, Vb, kf, vf);
  attn_kernel<<<512, 256, 0, stream>>>(Qb, Kb, Vb, wbp, Cb);
  oproj_gemm<<<dim3(16, 32), 256, 0, stream>>>(Cb, Wob, bo, out_f);
}